// Round 8
// baseline (130.265 us; speedup 1.0000x reference)
//
#include <hip/hip_runtime.h>
#include <hip/hip_fp16.h>

// B=16, Q=256, K=256, H=256, DV=256
#define Bn 16
#define Qn 256
#define Kn 256
#define Hn 256
#define DVn 256

constexpr float C2    = 2.8853900817779268f;   // 2/ln2 : e^{2x} = 2^(C2*x)
constexpr float LOG2E = 1.4426950408889634f;

typedef __attribute__((ext_vector_type(8))) short   bf16x8;
typedef __attribute__((ext_vector_type(8))) _Float16 halfx8;
typedef __attribute__((ext_vector_type(4))) float   f32x4;

__device__ __forceinline__ float fast_exp2(float x) { return __builtin_amdgcn_exp2f(x); }
__device__ __forceinline__ float fast_rcp(float x)  { return __builtin_amdgcn_rcpf(x); }

__device__ __forceinline__ unsigned short f2bf(float x) {   // RNE fp32->bf16
    unsigned u = __float_as_uint(x);
    u += 0x7fffu + ((u >> 16) & 1u);
    return (unsigned short)(u >> 16);
}

// ------------------------------------------------------------------
// K0 prep (grid 1280):
//  blocks <1024 : Xb = bf16(queries ++ keys) [8192][256], Wb = bf16(W_q ++ W_k)
//  blocks >=1024: Vt = f16(V^T) per batch: Vt[b][dv][k]  (LDS 64x64 tile transpose)
// ------------------------------------------------------------------
__global__ __launch_bounds__(256)
void prep_kernel(const float* __restrict__ q, const float* __restrict__ kx,
                 const float* __restrict__ wq, const float* __restrict__ wk,
                 const float* __restrict__ V,
                 unsigned short* __restrict__ Xb, unsigned short* __restrict__ Wb,
                 _Float16* __restrict__ Vt)
{
    __shared__ _Float16 T[64][72];
    const int tid = threadIdx.x;
    const int bx  = blockIdx.x;
    if (bx < 1024) {
        const int g = bx * 256 + tid;   // 0..262143
        {
            const float* xs = (g < 131072) ? (q + (size_t)g * 8)
                                           : (kx + (size_t)(g - 131072) * 8);
            float4 x0 = *(const float4*)xs;
            float4 x1 = *(const float4*)(xs + 4);
            ushort4 o0, o1;
            o0.x = f2bf(x0.x); o0.y = f2bf(x0.y); o0.z = f2bf(x0.z); o0.w = f2bf(x0.w);
            o1.x = f2bf(x1.x); o1.y = f2bf(x1.y); o1.z = f2bf(x1.z); o1.w = f2bf(x1.w);
            *(ushort4*)(Xb + (size_t)g * 8)     = o0;
            *(ushort4*)(Xb + (size_t)g * 8 + 4) = o1;
        }
        if (g < 32768) {
            const float* ws = (g < 16384) ? (wq + (size_t)g * 4)
                                          : (wk + (size_t)(g - 16384) * 4);
            float4 w0 = *(const float4*)ws;
            ushort4 o;
            o.x = f2bf(w0.x); o.y = f2bf(w0.y); o.z = f2bf(w0.z); o.w = f2bf(w0.w);
            *(ushort4*)(Wb + (size_t)g * 4) = o;
        }
        return;
    }
    // ---- V transpose tile ----
    const int tb  = bx - 1024;          // 0..255
    const int b   = tb >> 4;
    const int t2  = tb & 15;
    const int kt  = t2 >> 2, dvt = t2 & 3;
    {
        const int kk = tid >> 2, c4 = (tid & 3) * 16;
        const float* src = V + ((size_t)(b * Kn + kt * 64 + kk)) * DVn + dvt * 64 + c4;
        #pragma unroll
        for (int j4 = 0; j4 < 4; ++j4) {
            float4 v = *(const float4*)(src + j4 * 4);
            T[c4 + j4*4 + 0][kk] = (_Float16)v.x;
            T[c4 + j4*4 + 1][kk] = (_Float16)v.y;
            T[c4 + j4*4 + 2][kk] = (_Float16)v.z;
            T[c4 + j4*4 + 3][kk] = (_Float16)v.w;
        }
    }
    __syncthreads();
    {
        const int d = tid >> 2, kc = (tid & 3) * 16;
        const uint4* srcl = (const uint4*)&T[d][kc];
        uint4* dst = (uint4*)(Vt + (size_t)b * (DVn * Kn) + (size_t)(dvt * 64 + d) * Kn + kt * 64 + kc);
        dst[0] = srcl[0];
        dst[1] = srcl[1];
    }
}

// ------------------------------------------------------------------
// K1 proj (MFMA): rows 0..4095 = queries @ W_q^T -> Eq = exp(2*.) fp32 [4096][256]
//                 rows 4096..8191 = keys @ W_k^T -> Ek bf16 interleaved [b][h/4][k][4]
// ------------------------------------------------------------------
__global__ __launch_bounds__(256)
void proj_mfma_kernel(const unsigned short* __restrict__ Xb,
                      const unsigned short* __restrict__ Wb,
                      float* __restrict__ Eq, unsigned short* __restrict__ Ekb)
{
    const int tid  = threadIdx.x;
    const int wvid = tid >> 6, lane = tid & 63;
    const int m0   = blockIdx.x * 16;          // 0..8191
    const int n0   = wvid * 64;
    const bool isQ = (m0 < 4096);
    const int r16  = lane & 15, q8 = (lane >> 4) * 8;

    const unsigned short* Xrow  = Xb + (size_t)(m0 + r16) * 256 + q8;
    const unsigned short* Wbase = Wb + (isQ ? 0 : 65536);

    bf16x8 afr[8];
    #pragma unroll
    for (int s = 0; s < 8; ++s) afr[s] = *(const bf16x8*)(Xrow + s * 32);

    f32x4 acc[4];
    #pragma unroll
    for (int nt = 0; nt < 4; ++nt) {
        const unsigned short* Wrow = Wbase + (size_t)(n0 + nt * 16 + r16) * 256 + q8;
        f32x4 c = {0.f, 0.f, 0.f, 0.f};
        #pragma unroll
        for (int s = 0; s < 8; ++s) {
            bf16x8 bfr = *(const bf16x8*)(Wrow + s * 32);
            c = __builtin_amdgcn_mfma_f32_16x16x32_bf16(afr[s], bfr, c, 0, 0, 0);
        }
        acc[nt] = c;
    }
    const int rbase = (lane >> 4) * 4;
    #pragma unroll
    for (int nt = 0; nt < 4; ++nt) {
        const int n = n0 + nt * 16 + r16;
        #pragma unroll
        for (int r = 0; r < 4; ++r) {
            const int m = m0 + rbase + r;
            const float val = fast_exp2(C2 * acc[nt][r]);
            if (isQ) {
                Eq[(size_t)m * 256 + n] = val;
            } else {
                const int kr = m - 4096, b = kr >> 8, kk = kr & 255;
                Ekb[(((size_t)(b * 64 + (n >> 2))) * 256 + kk) * 4 + (n & 3)] = f2bf(val);
            }
        }
    }
}

// ------------------------------------------------------------------
// K2 scores: scores + softmax -> P (f16, normalized) [b][q][k]
// grid (Q/4=64, B=16), block 256. Thread t owns k-column t for 4 q-rows.
//   score(q,k) = -2 * sum_h wv[h] * rcp(1 + Eq[q,h]*Ek[k,h])  (softmax shift-inv)
// eq/wv: block-uniform global reads -> s_load. ek: bf16 dwordx2 prefetched.
// ------------------------------------------------------------------
__global__ __launch_bounds__(256)
void scores_kernel(const float* __restrict__ Eq, const unsigned short* __restrict__ Ekb,
                   const float* __restrict__ wv, _Float16* __restrict__ P)
{
    const int b  = blockIdx.y;
    const int q0 = blockIdx.x * 4;
    __shared__ float sredM[4][4];
    __shared__ float sredS[4][4];
    const int tid = threadIdx.x;

    const float* eq0 = Eq + (size_t)(b * Qn + q0) * Hn;   // block-uniform base

    float sc[4] = {0.f, 0.f, 0.f, 0.f};
    const uint2* ekp = (const uint2*)Ekb + (size_t)b * 16384 + tid;  // [b][h/4][k] quads
    uint2 e[4];
    #pragma unroll
    for (int g = 0; g < 4; ++g) e[g] = ekp[g * 256];
    for (int it = 0; it < 16; ++it) {
        uint2 en[4];
        if (it < 15) {
            #pragma unroll
            for (int g = 0; g < 4; ++g) en[g] = ekp[(4 * (it + 1) + g) * 256];
        }
        const int h0 = it * 16;
        float ek[16];
        #pragma unroll
        for (int g = 0; g < 4; ++g) {
            ek[4*g+0] = __uint_as_float(e[g].x << 16);
            ek[4*g+1] = __uint_as_float(e[g].x & 0xFFFF0000u);
            ek[4*g+2] = __uint_as_float(e[g].y << 16);
            ek[4*g+3] = __uint_as_float(e[g].y & 0xFFFF0000u);
        }
        #pragma unroll
        for (int g = 0; g < 4; ++g) {
            const float4 wa = *(const float4*)(wv + h0 + 4 * g);       // uniform -> s_load
            #pragma unroll
            for (int qq = 0; qq < 4; ++qq) {
                const float4 ea = *(const float4*)(eq0 + qq * 256 + h0 + 4 * g);  // uniform
                float a = sc[qq];
                a = fmaf(wa.x, fast_rcp(fmaf(ea.x, ek[4*g+0], 1.f)), a);
                a = fmaf(wa.y, fast_rcp(fmaf(ea.y, ek[4*g+1], 1.f)), a);
                a = fmaf(wa.z, fast_rcp(fmaf(ea.z, ek[4*g+2], 1.f)), a);
                a = fmaf(wa.w, fast_rcp(fmaf(ea.w, ek[4*g+3], 1.f)), a);
                sc[qq] = a;
            }
        }
        #pragma unroll
        for (int g = 0; g < 4; ++g) e[g] = en[g];
    }

    // ---- softmax over k (scores = -2*sc) ----
    const int w = tid >> 6, lane = tid & 63;
    #pragma unroll
    for (int qq = 0; qq < 4; ++qq) {
        sc[qq] = -2.0f * sc[qq];
        float mx = sc[qq];
        #pragma unroll
        for (int off = 32; off; off >>= 1) mx = fmaxf(mx, __shfl_xor(mx, off, 64));
        if (lane == 0) sredM[qq][w] = mx;
    }
    __syncthreads();
    float pq[4];
    #pragma unroll
    for (int qq = 0; qq < 4; ++qq) {
        const float mx = fmaxf(fmaxf(sredM[qq][0], sredM[qq][1]),
                               fmaxf(sredM[qq][2], sredM[qq][3]));
        pq[qq] = fast_exp2(LOG2E * (sc[qq] - mx));
        float s = pq[qq];
        #pragma unroll
        for (int off = 32; off; off >>= 1) s += __shfl_xor(s, off, 64);
        if (lane == 0) sredS[qq][w] = s;
    }
    __syncthreads();
    #pragma unroll
    for (int qq = 0; qq < 4; ++qq) {
        const float rinv = fast_rcp(sredS[qq][0] + sredS[qq][1] + sredS[qq][2] + sredS[qq][3]);
        P[(size_t)(b * Qn + q0 + qq) * Kn + tid] = (_Float16)(pq[qq] * rinv);
    }
}

// ------------------------------------------------------------------
// K3 PV (MFMA f16): out[b][q][dv] = P[b] @ Vt[b]^T  (Vt is [dv][k])
// grid 512: block covers 16 q x 128 dv; wave = 32 dv (2 MFMA n-tiles), K=256.
// ------------------------------------------------------------------
__global__ __launch_bounds__(256)
void pv_mfma_kernel(const _Float16* __restrict__ P, const _Float16* __restrict__ Vt,
                    float* __restrict__ out)
{
    const int tid  = threadIdx.x;
    const int wvid = tid >> 6, lane = tid & 63;
    const int bx   = blockIdx.x;
    const int b    = bx >> 5;
    const int t2   = bx & 31;
    const int q0   = (t2 >> 1) * 16;
    const int nb   = (t2 & 1) * 128 + wvid * 32;
    const int r16  = lane & 15, q8 = (lane >> 4) * 8;

    const _Float16* Prow = P + (size_t)b * (Qn * Kn) + (size_t)(q0 + r16) * Kn + q8;
    halfx8 afr[8];
    #pragma unroll
    for (int s = 0; s < 8; ++s) afr[s] = *(const halfx8*)(Prow + s * 32);

    f32x4 acc[2];
    #pragma unroll
    for (int nt = 0; nt < 2; ++nt) {
        const _Float16* Vrow = Vt + (size_t)b * (DVn * Kn) + (size_t)(nb + nt * 16 + r16) * Kn + q8;
        f32x4 c = {0.f, 0.f, 0.f, 0.f};
        #pragma unroll
        for (int s = 0; s < 8; ++s) {
            halfx8 bfr = *(const halfx8*)(Vrow + s * 32);
            c = __builtin_amdgcn_mfma_f32_16x16x32_f16(afr[s], bfr, c, 0, 0, 0);
        }
        acc[nt] = c;
    }
    const int rbase = (lane >> 4) * 4;
    #pragma unroll
    for (int nt = 0; nt < 2; ++nt) {
        const int n = nb + nt * 16 + r16;
        #pragma unroll
        for (int r = 0; r < 4; ++r) {
            out[(size_t)(b * Qn + q0 + rbase + r) * DVn + n] = acc[nt][r];
        }
    }
}

extern "C" void kernel_launch(void* const* d_in, const int* in_sizes, int n_in,
                              void* d_out, int out_size, void* d_ws, size_t ws_size,
                              hipStream_t stream) {
    const float* queries = (const float*)d_in[0];  // [16,256,256]
    const float* keys    = (const float*)d_in[1];  // [16,256,256]
    const float* values  = (const float*)d_in[2];  // [16,256,256]
    const float* W_q     = (const float*)d_in[3];  // [256,256]
    const float* W_k     = (const float*)d_in[4];  // [256,256]
    const float* w_v     = (const float*)d_in[5];  // [256]
    float* out = (float*)d_out;

    // workspace: Eq fp32 4MB | Ekb bf16 2MB | Xb bf16 4MB | Wb bf16 .25MB | Vt f16 2MB | P f16 2MB
    char* wsb = (char*)d_ws;
    float*          Eq  = (float*)(wsb);
    unsigned short* Ekb = (unsigned short*)(wsb + (4u << 20));
    unsigned short* Xb  = (unsigned short*)(wsb + (6u << 20));
    unsigned short* Wb  = (unsigned short*)(wsb + (10u << 20));
    _Float16*       Vt  = (_Float16*)(wsb + (10u << 20) + (256u << 10));
    _Float16*       P   = (_Float16*)(wsb + (12u << 20) + (256u << 10));

    prep_kernel<<<dim3(1280), 256, 0, stream>>>(queries, keys, W_q, W_k, values,
                                                Xb, Wb, Vt);
    proj_mfma_kernel<<<dim3(512), 256, 0, stream>>>(Xb, Wb, Eq, Ekb);
    scores_kernel<<<dim3(64, 16), 256, 0, stream>>>(Eq, Ekb, w_v, P);
    pv_mfma_kernel<<<dim3(512), 256, 0, stream>>>(P, Vt, out);
}